// Round 10
// baseline (70.790 us; speedup 1.0000x reference)
//
#include <hip/hip_runtime.h>
#include <hip/hip_bf16.h>

#define BATCH 8
#define SEQ   4096
#define NST   512     // state dim == GEMM K
#define DM    512     // d_model  == GEMM N
#define NCHUNK 64
#define TCH    64     // SEQ / NCHUNK
#define NSUB   4      // sub-chunks per block (two-level scan)
#define RSUB   16     // rows per sub-chunk
#define LDP    (NST + 8)   // LDS row pitch in shorts (2-way bank alias only)

typedef __attribute__((ext_vector_type(4))) float f32x4;
typedef __attribute__((ext_vector_type(8))) short short8v;   // 8 bf16
typedef __attribute__((ext_vector_type(4))) short short4v;

__device__ __forceinline__ short f2bf(float f) {
  union { float f; unsigned u; } v; v.f = f;
  unsigned r = v.u + 0x7FFFu + ((v.u >> 16) & 1u);   // RNE truncate to bf16
  return (short)(r >> 16);
}

// K1: per-chunk local scan sums S[c][b][n]; thread owns 4 cols, f32x4 loads
__global__ void k_scan_sums(const float* __restrict__ u, const float* __restrict__ Lam,
                            const float* __restrict__ Bv, const float* __restrict__ log_dt,
                            float* __restrict__ S) {
  int gid = blockIdx.x * 128 + threadIdx.x;      // [0, NCHUNK*BATCH*128)
  int n0 = (gid & 127) * 4;
  int bc = gid >> 7;
  int b  = bc & (BATCH - 1);
  int c  = bc >> 3;
  float dt = expf(log_dt[0]);
  f32x4 lam = *(const f32x4*)(Lam + n0);
  f32x4 bv  = *(const f32x4*)(Bv + n0);
  float a[4], g[4];
  #pragma unroll
  for (int i = 0; i < 4; ++i) { a[i] = expf(-dt * expf(lam[i])); g[i] = dt * bv[i]; }
  const float* up = u + ((size_t)b * SEQ + (size_t)c * TCH) * NST + n0;
  f32x4 s = (f32x4){0.f, 0.f, 0.f, 0.f};
  #pragma unroll 8
  for (int t = 0; t < TCH; ++t) {
    f32x4 v = *(const f32x4*)(up + (size_t)t * NST);
    #pragma unroll
    for (int i = 0; i < 4; ++i) s[i] = fmaf(a[i], s[i], g[i] * v[i]);
  }
  *(f32x4*)(S + (c * BATCH + b) * NST + n0) = s;
}

// K2: sequential chunk-state propagation: Xc[c] = incoming state of chunk c
__global__ void k_propagate(const float* __restrict__ Lam, const float* __restrict__ log_dt,
                            const float* __restrict__ S, float* __restrict__ Xc) {
  int gid = blockIdx.x * 256 + threadIdx.x;      // [0, BATCH*NST)
  int n = gid & (NST - 1);
  int b = gid >> 9;
  float dt = expf(log_dt[0]);
  float a  = expf(-dt * expf(Lam[n]));
  float aT = a;
  #pragma unroll
  for (int i = 0; i < 6; ++i) aT *= aT;          // a^64 = a^TCH
  float x = 0.f;
  for (int c = 0; c < NCHUNK; ++c) {
    Xc[(c * BATCH + b) * NST + n] = x;
    x = fmaf(aT, x, S[(c * BATCH + b) * NST + n]);
  }
}

// K3: Qt[d][n] = bf16(Q[n][d]) via LDS tile transpose (coalesced both sides)
__global__ void k_transQ(const float* __restrict__ Q, short* __restrict__ Qt) {
  __shared__ short tile[64][68];
  int bn = (blockIdx.x & 7) * 64;                // n tile base
  int bd = (blockIdx.x >> 3) * 64;               // d tile base
  int tc = threadIdx.x & 15;                     // 16 col-quads
  int tr = threadIdx.x >> 4;                     // 16 rows per pass
  #pragma unroll
  for (int i = 0; i < 4; ++i) {
    int r = tr + i * 16;                         // n-local
    f32x4 v = *(const f32x4*)(Q + (size_t)(bn + r) * DM + bd + tc * 4);
    short4v h;
    h[0] = f2bf(v[0]); h[1] = f2bf(v[1]); h[2] = f2bf(v[2]); h[3] = f2bf(v[3]);
    *(short4v*)&tile[r][tc * 4] = h;
  }
  __syncthreads();
  #pragma unroll
  for (int i = 0; i < 4; ++i) {
    int r = tr + i * 16;                         // d-local
    short4v h;
    #pragma unroll
    for (int j = 0; j < 4; ++j) h[j] = tile[tc * 4 + j][r];
    *(short4v*)(Qt + (size_t)(bd + r) * NST + bn + tc * 4) = h;
  }
}

// K4 fused: TWO-LEVEL vectorized scan -> LDS bf16 -> 64x512x512 GEMM -> y.
// Thread (tq,q) owns rows [tq*16,tq*16+16) x cols [4q,4q+4): f32x4 u loads
// (16B/lane), 4 parallel 16-step chains, LDS sub-chunk-sum exchange, a^16
// combine + a^{j+1} correction, short4v X writes. GEMM phase unchanged (r9).
// LDS 74752 B -> 2 blocks/CU; VGPR target ~95 (<128 cap at 4 waves/SIMD).
__global__ __launch_bounds__(512) void k_fused(
    const float* __restrict__ u, const float* __restrict__ Lam,
    const float* __restrict__ Bv, const float* __restrict__ log_dt,
    const float* __restrict__ Xc, const short* __restrict__ Qt,
    float* __restrict__ y) {
  __shared__ __align__(16) short X[TCH][LDP];    // 66560 B
  __shared__ __align__(16) float Ssub[NSUB][NST]; // 8192 B sub-chunk sums
  const int tid = threadIdx.x;
  const int b = blockIdx.x & (BATCH - 1);
  const int c = blockIdx.x >> 3;
  const int tq = tid >> 7;                       // sub-chunk 0..3
  const int q  = tid & 127;                      // col group
  const int n0 = q * 4;

  // ---- phase 1: two-level scan ----
  {
    const float dt = expf(log_dt[0]);
    f32x4 lam = *(const f32x4*)(Lam + n0);
    f32x4 bv  = *(const f32x4*)(Bv + n0);
    float a[4], g[4], a16[4];
    #pragma unroll
    for (int i = 0; i < 4; ++i) {
      a[i] = expf(-dt * expf(lam[i]));
      g[i] = dt * bv[i];
      float t = a[i]; t *= t; t *= t; t *= t; t *= t;   // a^16
      a16[i] = t;
    }
    // seed: tq=0 starts from chunk-incoming state, others from 0
    f32x4 seed = (f32x4){0.f, 0.f, 0.f, 0.f};
    if (tq == 0) seed = *(const f32x4*)(Xc + (c * BATCH + b) * NST + n0);

    const float* up = u + ((size_t)b * SEQ + (size_t)(c * TCH + tq * RSUB)) * NST + n0;
    f32x4 v[RSUB];
    #pragma unroll
    for (int j = 0; j < RSUB; ++j) v[j] = *(const f32x4*)(up + (size_t)j * NST);

    // local scan (seeded for tq=0)
    f32x4 x = seed;
    #pragma unroll
    for (int j = 0; j < RSUB; ++j) {
      #pragma unroll
      for (int i = 0; i < 4; ++i) x[i] = fmaf(a[i], x[i], g[i] * v[j][i]);
      v[j] = x;
    }
    *(f32x4*)&Ssub[tq][n0] = x;                  // sub-chunk end state
    __syncthreads();

    // correction for tq>=1: I(tq) = a16*I(tq-1) + Ssub[tq-1], I(1)=Ssub[0]
    if (tq > 0) {
      f32x4 I = *(const f32x4*)&Ssub[0][n0];
      for (int s = 1; s < tq; ++s) {
        f32x4 sv = *(const f32x4*)&Ssub[s][n0];
        #pragma unroll
        for (int i = 0; i < 4; ++i) I[i] = fmaf(a16[i], I[i], sv[i]);
      }
      f32x4 ap;
      #pragma unroll
      for (int i = 0; i < 4; ++i) ap[i] = a[i];
      #pragma unroll
      for (int j = 0; j < RSUB; ++j) {
        #pragma unroll
        for (int i = 0; i < 4; ++i) {
          v[j][i] = fmaf(ap[i], I[i], v[j][i]);
          ap[i] *= a[i];
        }
      }
    }
    // write corrected rows to X as bf16 (8B/lane stores)
    #pragma unroll
    for (int j = 0; j < RSUB; ++j) {
      short4v h;
      h[0] = f2bf(v[j][0]); h[1] = f2bf(v[j][1]);
      h[2] = f2bf(v[j][2]); h[3] = f2bf(v[j][3]);
      *(short4v*)&X[tq * RSUB + j][n0] = h;
    }
  }
  __syncthreads();

  // ---- phase 2: GEMM 64x512x512; wave wc owns 64 cols x all 64 rows ----
  const int lane = tid & 63;
  const int wc   = tid >> 6;                     // 0..7
  const int l15  = lane & 15;
  const int lhi  = lane >> 4;
  const int ka   = lhi * 8;                      // k offset within BK=32
  const short* qbase = Qt + (size_t)(wc * 64 + l15) * NST + ka;
  float* yb = y + ((size_t)b * SEQ + (size_t)c * TCH) * DM;

  f32x4 acc[4][4];
  #pragma unroll
  for (int mi = 0; mi < 4; ++mi)
    #pragma unroll
    for (int nf = 0; nf < 4; ++nf) acc[mi][nf] = (f32x4){0.f, 0.f, 0.f, 0.f};

  #pragma unroll 4
  for (int kk = 0; kk < 16; ++kk) {
    const int k0 = kk * 32;
    short8v afrag[4];
    #pragma unroll
    for (int mi = 0; mi < 4; ++mi)
      afrag[mi] = *(const short8v*)&X[mi * 16 + l15][k0 + ka];
    short8v bfrag[4];
    #pragma unroll
    for (int nf = 0; nf < 4; ++nf)
      bfrag[nf] = *(const short8v*)(qbase + (size_t)nf * 16 * NST + k0);
    #pragma unroll
    for (int mi = 0; mi < 4; ++mi)
      #pragma unroll
      for (int nf = 0; nf < 4; ++nf)
        acc[mi][nf] = __builtin_amdgcn_mfma_f32_16x16x32_bf16(afrag[mi], bfrag[nf], acc[mi][nf], 0, 0, 0);
  }

  // ---- y stores ----
  #pragma unroll
  for (int mi = 0; mi < 4; ++mi)
    #pragma unroll
    for (int nf = 0; nf < 4; ++nf) {
      const int rr = mi * 16 + lhi * 4;
      const int cc = wc * 64 + nf * 16 + l15;
      #pragma unroll
      for (int i = 0; i < 4; ++i)
        yb[(size_t)(rr + i) * DM + cc] = acc[mi][nf][i];
    }
}

extern "C" void kernel_launch(void* const* d_in, const int* in_sizes, int n_in,
                              void* d_out, int out_size, void* d_ws, size_t ws_size,
                              hipStream_t stream) {
  const float* u      = (const float*)d_in[0];
  const float* Lam    = (const float*)d_in[1];
  const float* Bv     = (const float*)d_in[2];
  const float* Q      = (const float*)d_in[3];
  const float* log_dt = (const float*)d_in[4];
  float* out = (float*)d_out;

  float* S  = (float*)d_ws;                                  // 1 MB
  float* Xc = S + NCHUNK * BATCH * NST;                      // 1 MB
  short* Qt = (short*)(Xc + NCHUNK * BATCH * NST);           // 512 KB bf16

  hipLaunchKernelGGL(k_transQ, dim3(64), dim3(256), 0, stream, Q, Qt);
  hipLaunchKernelGGL(k_scan_sums, dim3(NCHUNK * BATCH), dim3(128), 0, stream,
                     u, Lam, Bv, log_dt, S);
  hipLaunchKernelGGL(k_propagate, dim3(BATCH * NST / 256), dim3(256), 0, stream,
                     Lam, log_dt, S, Xc);
  hipLaunchKernelGGL(k_fused, dim3(NCHUNK * BATCH), dim3(512), 0, stream,
                     u, Lam, Bv, log_dt, Xc, Qt, out);
}